// Round 11
// baseline (283.369 us; speedup 1.0000x reference)
//
#include <hip/hip_runtime.h>
#include <hip/hip_bf16.h>
#include <stdint.h>

#define BATCH   16384
#define EXPERTS 8
#define IN_DIM  1024
#define OUT_DIM 1024

typedef unsigned short u16;
typedef short  bf16x8 __attribute__((ext_vector_type(8)));
typedef float  f32x4  __attribute__((ext_vector_type(4)));

__device__ __forceinline__ u16 f2bf(float f) {
  uint32_t u = __float_as_uint(f);
  u += 0x7fffu + ((u >> 16) & 1u);   // RNE
  return (u16)(u >> 16);
}

#define GLDS16(g, l)                                                      \
  __builtin_amdgcn_global_load_lds(                                       \
      (const __attribute__((address_space(1))) void*)(g),                 \
      (__attribute__((address_space(3))) void*)(l), 16, 0, 0)

#define MFMA_BF16 __builtin_amdgcn_mfma_f32_16x16x32_bf16
#define SB0 __builtin_amdgcn_sched_barrier(0)
#define LGKM(N) asm volatile("s_waitcnt lgkmcnt(" #N ")" ::: "memory")
#define VM0     asm volatile("s_waitcnt vmcnt(0)" ::: "memory")

// ---------------- kernel 1: x fp32 -> bf16 ----------------
__global__ void cvt_x(const float* __restrict__ x, u16* __restrict__ xb) {
  size_t i = ((size_t)blockIdx.x * 256 + threadIdx.x) * 4;
  float4 v = *reinterpret_cast<const float4*>(x + i);
  ushort4 o;
  o.x = f2bf(v.x); o.y = f2bf(v.y); o.z = f2bf(v.z); o.w = f2bf(v.w);
  *reinterpret_cast<ushort4*>(xb + i) = o;
}

// ------- kernel 2: W[e][i][o] fp32 -> Wbt[e][o][i] bf16 (transpose) -------
__global__ void cvt_w(const float* __restrict__ W, u16* __restrict__ wbt) {
  __shared__ u16 t[64][72];
  const int e  = blockIdx.z;
  const int i0 = blockIdx.x * 64;
  const int o0 = blockIdx.y * 64;
  const int tid = threadIdx.x;
  const int c  = (tid & 15) * 4;
  const int r_ = tid >> 4;
  const float* src = W + ((size_t)e << 20);
#pragma unroll
  for (int p = 0; p < 4; ++p) {
    int r = r_ + p * 16;
    float4 v = *reinterpret_cast<const float4*>(src + (size_t)(i0 + r) * 1024 + o0 + c);
    t[r][c + 0] = f2bf(v.x); t[r][c + 1] = f2bf(v.y);
    t[r][c + 2] = f2bf(v.z); t[r][c + 3] = f2bf(v.w);
  }
  __syncthreads();
  u16* dst = wbt + ((size_t)e << 20);
#pragma unroll
  for (int p = 0; p < 4; ++p) {
    int orow = r_ + p * 16;
    ushort4 u;
    u.x = t[c + 0][orow]; u.y = t[c + 1][orow];
    u.z = t[c + 2][orow]; u.w = t[c + 3][orow];
    *reinterpret_cast<ushort4*>(dst + (size_t)(o0 + orow) * 1024 + i0 + c) = u;
  }
}

// ---------------- kernel 3: Horner GEMM, mid-tile publish barrier ---------
// BM=BN=256 BK=64, 512 thr = 8 waves (2M x 4N), wave 128x64, acc 128 VGPR.
// Two barriers/tile: MID (vmcnt(0) first: publishes parity-q staging, issued
// at tile top -> 2 clusters of cover) and END (recycle gate, lgkm-only).
// Next-tile F0' reads issue AFTER mid-barrier, hidden under P2 -> every read
// group hides under a MFMA cluster, cyclically across tiles.
// DS ledger (in-order): carry F0(8) | top +F1(4)=12 | LGKM(4)->F0 | +F2(8)=12
// P0 | LGKM(8)->F1 | +F3(4)=12 | VM0 MID | LGKM(4)->F2 | +F0'(8)=12 P2 |
// LGKM(8)->F3 | P3 | END.  Parity-p reads all drained at END; outstanding
// F0' is parity q, whose buffer is rewritten only after the NEXT mid-barrier.
// LDS (u16 elems): A dbuf @0,@16384; B dbuf @32768,@49152; rl @65536 (4096).
__global__ __launch_bounds__(512, 2)
void zgemm(const u16* __restrict__ xb, const u16* __restrict__ wbt,
           const float* __restrict__ wts, const float* __restrict__ bias,
           float* __restrict__ y) {
  __shared__ u16 sm[69632];
  char* smb = (char*)sm;
  float* rl = (float*)(sm + 65536);          // byte 131072

  const int tid = threadIdx.x;
  const int l   = tid & 63;
  const int w   = tid >> 6;
  const int wm  = w >> 2;                    // 0..1
  const int wn  = w & 3;                     // 0..3
  const int x8  = blockIdx.x & 7;            // XCD residue
  const int jj  = blockIdx.x >> 3;           // 0..31
  const int n0  = (x8 >> 1) * 256;           // XCD-pair owns one B-panel
  const int b0  = (((x8 & 1) << 5) + jj) << 8;

  // ---- ratio table rl[e][256]: e<7 -> w'_e/w'_{e+1}; rl[7] = w'_7
#pragma unroll
  for (int i = 0; i < 4; ++i) {
    const int flat = tid + i * 512;
    const int e = flat & 7, r = flat >> 3;
    const float* wr = wts + (size_t)(b0 + r) * EXPERTS;
    float we = fmaxf(wr[e], 1e-20f);
    float rr = (e < 7) ? we / fmaxf(wr[e + 1], 1e-20f) : we;
    rl[e * 256 + r] = rr;
  }

  // ---- staging geometry (pre-swizzled global source, linear GLDS dest)
  const int rb    = (w << 3) + (l >> 3);              // 0..63
  const int chunk = ((l & 7) ^ (l >> 3)) << 3;
  const u16* pAg = xb  + (size_t)(b0 + rb) * IN_DIM + chunk;
  const u16* pBg = wbt + (size_t)(n0 + rb) * 1024 + chunk;

  // ---- fragment read keys
  const int l15  = l & 15;
  const int kb0  = (((l >> 4) << 4)) ^ ((l & 7) << 4);   // kf0; kf1 = ^64
  const int arow = (wm * 128 + l15) * 128;               // + m*2048
  const int brow = (wn * 64 + l15) * 128;                // + n*2048
  const int wlo  = (wm << 9) + ((l >> 4) << 4);          // rl byte off + m*64

  f32x4 acc[8][4];
#pragma unroll
  for (int m = 0; m < 8; ++m)
#pragma unroll
    for (int n = 0; n < 4; ++n) acc[m][n] = (f32x4){0.f, 0.f, 0.f, 0.f};

#define STG_A(q, dstE, ev_kv)                                              \
  GLDS16(pAg + (size_t)((q) * 64) * 1024 + (ev_kv),                        \
         sm + (dstE) + (q) * 4096 + (w << 9))
#define STG_B(q, dstE, off)                                                \
  GLDS16(pBg + (off) + (size_t)((q) * 64) * 1024,                          \
         sm + (dstE) + (q) * 4096 + (w << 9))

#define MM(AV, BV, MB)                                                     \
  __builtin_amdgcn_s_setprio(1);                                           \
  _Pragma("unroll")                                                        \
  for (int m = 0; m < 4; ++m)                                              \
    _Pragma("unroll")                                                      \
    for (int n = 0; n < 4; ++n)                                            \
      acc[(MB) + m][n] = MFMA_BF16(AV[m], BV[n], acc[(MB) + m][n], 0, 0, 0); \
  __builtin_amdgcn_s_setprio(0);

  // ---- prologue: tile 0 -> parity-0; drain; publish; issue F0(tile 0)
  STG_A(0, 0, 0); STG_A(1, 0, 0); STG_A(2, 0, 0); STG_A(3, 0, 0);
  STG_B(0, 32768, 0); STG_B(1, 32768, 0); STG_B(2, 32768, 0); STG_B(3, 32768, 0);
  VM0;
  LGKM(0);                                   // rl ds_writes drained
  __builtin_amdgcn_s_barrier();

  bf16x8 a0[4], b0v[4];                      // loop-carried F0 fragments
#pragma unroll
  for (int m = 0; m < 4; ++m)
    a0[m] = *(const bf16x8*)(smb + arow + m * 2048 + kb0);
#pragma unroll
  for (int n = 0; n < 4; ++n)
    b0v[n] = *(const bf16x8*)(smb + 65536 + brow + n * 2048 + kb0);

#pragma unroll 1
  for (int t = 0; t < 128; ++t) {
    const int tn  = (t + 1) & 127;                 // wrap (harmless garbage)
    const int e1  = tn >> 4, k1 = tn & 15;
    const int ArB  = (t & 1) << 15;                // parity-p read base (A)
    const int BrB  = 65536 + ((t & 1) << 15);      // parity-p read base (B)
    const int ArBn = ((t + 1) & 1) << 15;          // parity-q read base (A)
    const int BrBn = 65536 + (((t + 1) & 1) << 15);
    const int AwE  = ((t + 1) & 1) << 14;          // staging dest (elems)
    const int BwE  = 32768 + (((t + 1) & 1) << 14);
    const size_t aoffg = (size_t)k1 * 64;
    const size_t boffg = (size_t)e1 * 1048576 + (size_t)k1 * 64;

    bf16x8 a1[4], a2v[4], b1v[4], a3[4];

    // ---- top: stage tile t+1 (8 GLDS) + F1 reads
    STG_A(0, AwE, aoffg); STG_A(1, AwE, aoffg);
    STG_A(2, AwE, aoffg); STG_A(3, AwE, aoffg);
    STG_B(0, BwE, boffg); STG_B(1, BwE, boffg);
    STG_B(2, BwE, boffg); STG_B(3, BwE, boffg);
#pragma unroll
    for (int m = 0; m < 4; ++m)
      a1[m] = *(const bf16x8*)(smb + ArB + arow + (m + 4) * 2048 + kb0);

    LGKM(4); SB0;                          // F0 done (carry-in)
#pragma unroll
    for (int m = 0; m < 4; ++m)            // F2: a kf1 m0-3 + b kf1
      a2v[m] = *(const bf16x8*)(smb + ArB + arow + m * 2048 + (kb0 ^ 64));
#pragma unroll
    for (int n = 0; n < 4; ++n)
      b1v[n] = *(const bf16x8*)(smb + BrB + brow + n * 2048 + (kb0 ^ 64));
    MM(a0, b0v, 0)                         // P0

    LGKM(8); SB0;                          // F1 done
#pragma unroll
    for (int m = 0; m < 4; ++m)            // F3: a kf1 m4-7
      a3[m] = *(const bf16x8*)(smb + ArB + arow + (m + 4) * 2048 + (kb0 ^ 64));
    MM(a1, b0v, 4)                         // P1

    VM0;                                   // tile t+1 staging landed
    __builtin_amdgcn_s_barrier();          // MID: publish parity q

    LGKM(4); SB0;                          // F2 done
#pragma unroll
    for (int m = 0; m < 4; ++m)            // F0' of tile t+1 (parity q)
      a0[m] = *(const bf16x8*)(smb + ArBn + arow + m * 2048 + kb0);
#pragma unroll
    for (int n = 0; n < 4; ++n)
      b0v[n] = *(const bf16x8*)(smb + BrBn + brow + n * 2048 + kb0);
    MM(a2v, b1v, 0)                        // P2

    LGKM(8); SB0;                          // F3 done (F0' still in flight)
    MM(a3, b1v, 4)                         // P3

    // ---- expert boundary: acc *= w'_e / w'_{e+1} (7 times; flushes ledger)
    if ((t & 15) == 15 && t != 127) {
      const int e = t >> 4;
      f32x4 rv[8];
#pragma unroll
      for (int m = 0; m < 8; ++m)
        rv[m] = *(const f32x4*)(smb + 131072 + e * 1024 + wlo + m * 64);
      LGKM(0); SB0;                        // drains rl reads AND F0' (rare)
#pragma unroll
      for (int m = 0; m < 8; ++m)
#pragma unroll
        for (int n = 0; n < 4; ++n) acc[m][n] *= rv[m];
    }
    __builtin_amdgcn_s_barrier();          // END: recycle gate
  }
  VM0; LGKM(0);

  // ---- epilogue: y = w'_7 * acc + sum_e w_e * bias_e
  float bv[4][8];
#pragma unroll
  for (int n = 0; n < 4; ++n) {
    const int c = n0 + wn * 64 + n * 16 + l15;
#pragma unroll
    for (int ee = 0; ee < 8; ++ee) bv[n][ee] = bias[ee * OUT_DIM + c];
  }
#pragma unroll
  for (int m = 0; m < 8; ++m) {
    const f32x4 rv7 = *(const f32x4*)(smb + 131072 + 7 * 1024 + wlo + m * 64);
    const int r0 = b0 + wm * 128 + m * 16 + ((l >> 4) << 2);
#pragma unroll
    for (int j = 0; j < 4; ++j) {
      const float* wr = wts + (size_t)(r0 + j) * EXPERTS;
      float w8[8];
#pragma unroll
      for (int ee = 0; ee < 8; ++ee) w8[ee] = wr[ee];
#pragma unroll
      for (int n = 0; n < 4; ++n) {
        const int c = n0 + wn * 64 + n * 16 + l15;
        float v = acc[m][n][j] * rv7[j];
#pragma unroll
        for (int ee = 0; ee < 8; ++ee) v += w8[ee] * bv[n][ee];
        y[(size_t)(r0 + j) * OUT_DIM + c] = v;
      }
    }
  }
}

extern "C" void kernel_launch(void* const* d_in, const int* in_sizes, int n_in,
                              void* d_out, int out_size, void* d_ws, size_t ws_size,
                              hipStream_t stream) {
  const float* x    = (const float*)d_in[0];
  const float* wts  = (const float*)d_in[1];
  const float* W    = (const float*)d_in[2];
  const float* bias = (const float*)d_in[3];
  float* y = (float*)d_out;

  const size_t xb_elems = (size_t)BATCH * IN_DIM;                 // 32 MB bf16
  const size_t wb_elems = (size_t)EXPERTS * IN_DIM * OUT_DIM;     // 16 MB bf16
  if (ws_size < (xb_elems + wb_elems) * sizeof(u16)) return;      // loud failure
  u16* xb  = (u16*)d_ws;
  u16* wbt = xb + xb_elems;

  cvt_x<<<(BATCH * IN_DIM) / (4 * 256), 256, 0, stream>>>(x, xb);
  cvt_w<<<dim3(IN_DIM / 64, OUT_DIM / 64, EXPERTS), 256, 0, stream>>>(W, wbt);
  zgemm<<<dim3(256), 512, 0, stream>>>(xb, wbt, wts, bias, y);
}